// Round 1
// baseline (2748.396 us; speedup 1.0000x reference)
//
#include <hip/hip_runtime.h>

#define H_   512
#define T_   1000
#define B_   32
#define FIN_ 700

static __device__ __forceinline__ float clampAlpha(float a) {
    const float AMIN = 0.8187307530779818f;   // exp(-1/5)
    const float AMAX = 0.9607894391523232f;   // exp(-1/25)
    return fminf(fmaxf(a, AMIN), AMAX);
}

// ------------------------------------------------------------------
// C[m,n] = sum_k A[m,k] * Bt[n,k]   (A: [M,K] row-major, Bt: [N,K])
// 64x64 tile, BK=16, 256 threads, 4x4 microtile per thread.
// M % 64 == 0 and N % 64 == 0 assumed (true here). K edge guarded.
// ------------------------------------------------------------------
__global__ __launch_bounds__(256) void gemm_bt_kernel(
    const float* __restrict__ A, const float* __restrict__ Bt,
    float* __restrict__ C, int M, int N, int K)
{
    __shared__ __align__(16) float As[16][68];
    __shared__ __align__(16) float Bs[16][68];
    const int tid = threadIdx.x;
    const int bm = blockIdx.x * 64;
    const int bn = blockIdx.y * 64;
    const int tx = tid & 15, ty = tid >> 4;
    const int lrow = tid >> 2;          // 0..63
    const int lk   = (tid & 3) << 2;    // 0,4,8,12
    float acc[4][4] = {};
    const float* Arow = A + (size_t)(bm + lrow) * K;
    const float* Brow = Bt + (size_t)(bn + lrow) * K;

    for (int k0 = 0; k0 < K; k0 += 16) {
        const int ka = k0 + lk;
        float4 av, bv;
        if (ka + 3 < K) {
            av = *reinterpret_cast<const float4*>(Arow + ka);
            bv = *reinterpret_cast<const float4*>(Brow + ka);
        } else {
            float a_[4], b_[4];
            #pragma unroll
            for (int i = 0; i < 4; ++i) {
                a_[i] = (ka + i < K) ? Arow[ka + i] : 0.f;
                b_[i] = (ka + i < K) ? Brow[ka + i] : 0.f;
            }
            av = make_float4(a_[0], a_[1], a_[2], a_[3]);
            bv = make_float4(b_[0], b_[1], b_[2], b_[3]);
        }
        __syncthreads();
        As[lk + 0][lrow] = av.x; As[lk + 1][lrow] = av.y;
        As[lk + 2][lrow] = av.z; As[lk + 3][lrow] = av.w;
        Bs[lk + 0][lrow] = bv.x; Bs[lk + 1][lrow] = bv.y;
        Bs[lk + 2][lrow] = bv.z; Bs[lk + 3][lrow] = bv.w;
        __syncthreads();
        #pragma unroll
        for (int kk = 0; kk < 16; ++kk) {
            const float4 a4 = *reinterpret_cast<const float4*>(&As[kk][ty << 2]);
            const float4 b4 = *reinterpret_cast<const float4*>(&Bs[kk][tx << 2]);
            const float aa[4] = {a4.x, a4.y, a4.z, a4.w};
            const float bb[4] = {b4.x, b4.y, b4.z, b4.w};
            #pragma unroll
            for (int i = 0; i < 4; ++i)
                #pragma unroll
                for (int j = 0; j < 4; ++j)
                    acc[i][j] = fmaf(aa[i], bb[j], acc[i][j]);
        }
    }
    #pragma unroll
    for (int i = 0; i < 4; ++i) {
        const float4 r = make_float4(acc[i][0], acc[i][1], acc[i][2], acc[i][3]);
        *reinterpret_cast<float4*>(&C[(size_t)(bm + ty * 4 + i) * N + bn + tx * 4]) = r;
    }
}

// ------------------------------------------------------------------
// RLIF recurrence, one workgroup per batch. 256 threads, 2 units each.
// ut = a*(ut - st) + (1-a)*(wx_t + st@Vz); st = (ut > 1).
// st binary after step 0 -> gather-sum over active list in LDS.
// Diagonal zeroing via post-subtract st[j]*V[j][j].
// ------------------------------------------------------------------
__global__ __launch_bounds__(256) void rlif_kernel(
    const float* __restrict__ Wx,   // [B,T,H]
    const float* __restrict__ V,    // [H,H]
    const float* __restrict__ alpha,// [H]
    const float* __restrict__ ut0,  // [B,H]
    const float* __restrict__ st0,  // [B,H]
    float* __restrict__ s_out,      // [B,T,H]
    float* __restrict__ fire)       // [B,H] spike counts
{
    const int b = blockIdx.x;
    const int tid = threadIdx.x;
    const int j0 = tid * 2;
    __shared__ int act[H_];
    __shared__ int cnt;

    const float a0 = clampAlpha(alpha[j0]);
    const float a1 = clampAlpha(alpha[j0 + 1]);
    const float om0 = 1.f - a0, om1 = 1.f - a1;
    float u0 = ut0[b * H_ + j0], u1 = ut0[b * H_ + j0 + 1];
    float s0 = st0[b * H_ + j0], s1 = st0[b * H_ + j0 + 1];
    const float vd0 = V[(size_t)j0 * H_ + j0];
    const float vd1 = V[(size_t)(j0 + 1) * H_ + (j0 + 1)];
    float f0 = 0.f, f1 = 0.f;
    const float* wxb  = Wx + (size_t)b * T_ * H_;
    float*       sob  = s_out + (size_t)b * T_ * H_;
    const float* st0b = st0 + b * H_;
    int n_act = 0;
    __syncthreads();

    for (int t = 0; t < T_; ++t) {
        float rec0 = 0.f, rec1 = 0.f;
        if (t == 0) {
            // dense pass: st0 is real-valued
            for (int h = 0; h < H_; ++h) {
                const float s = st0b[h];
                const float2 v = *reinterpret_cast<const float2*>(&V[(size_t)h * H_ + j0]);
                rec0 = fmaf(s, v.x, rec0);
                rec1 = fmaf(s, v.y, rec1);
            }
        } else {
            for (int i = 0; i < n_act; ++i) {
                const int h = act[i];
                const float2 v = *reinterpret_cast<const float2*>(&V[(size_t)h * H_ + j0]);
                rec0 += v.x; rec1 += v.y;
            }
        }
        rec0 -= s0 * vd0;   // remove diagonal contribution
        rec1 -= s1 * vd1;
        const float2 wx = *reinterpret_cast<const float2*>(&wxb[(size_t)t * H_ + j0]);
        u0 = a0 * (u0 - s0) + om0 * (wx.x + rec0);
        u1 = a1 * (u1 - s1) + om1 * (wx.y + rec1);
        s0 = (u0 > 1.f) ? 1.f : 0.f;
        s1 = (u1 > 1.f) ? 1.f : 0.f;
        f0 += s0; f1 += s1;
        *reinterpret_cast<float2*>(&sob[(size_t)t * H_ + j0]) = make_float2(s0, s1);

        __syncthreads();                 // everyone done reading act
        if (tid == 0) cnt = 0;
        __syncthreads();                 // reset visible
        if (s0 != 0.f) { const int p = atomicAdd(&cnt, 1); act[p] = j0; }
        if (s1 != 0.f) { const int p = atomicAdd(&cnt, 1); act[p] = j0 + 1; }
        __syncthreads();                 // list complete
        n_act = cnt;
    }
    fire[b * H_ + j0]     = f0;
    fire[b * H_ + j0 + 1] = f1;
}

// ------------------------------------------------------------------
// Readout: ut = a*ut + (1-a)*wx_t; out += softmax(ut). One WG/batch.
// ------------------------------------------------------------------
__global__ __launch_bounds__(256) void readout_kernel(
    const float* __restrict__ Wx,   // [B,T,H]
    const float* __restrict__ alpha,
    const float* __restrict__ ut0,  // [B,H]
    float* __restrict__ out)        // [B,H]
{
    const int b = blockIdx.x;
    const int tid = threadIdx.x;
    const int j0 = tid * 2;
    __shared__ float red[8];
    const float a0 = clampAlpha(alpha[j0]);
    const float a1 = clampAlpha(alpha[j0 + 1]);
    const float om0 = 1.f - a0, om1 = 1.f - a1;
    float u0 = ut0[b * H_ + j0], u1 = ut0[b * H_ + j0 + 1];
    float o0 = 0.f, o1 = 0.f;
    const float* wxb = Wx + (size_t)b * T_ * H_;
    const int wave = tid >> 6;
    const int lane = tid & 63;

    for (int t = 0; t < T_; ++t) {
        const float2 wx = *reinterpret_cast<const float2*>(&wxb[(size_t)t * H_ + j0]);
        u0 = fmaf(a0, u0, om0 * wx.x);
        u1 = fmaf(a1, u1, om1 * wx.y);
        float m = fmaxf(u0, u1);
        #pragma unroll
        for (int off = 32; off > 0; off >>= 1)
            m = fmaxf(m, __shfl_xor(m, off, 64));
        if (lane == 0) red[wave] = m;
        __syncthreads();
        m = fmaxf(fmaxf(red[0], red[1]), fmaxf(red[2], red[3]));
        const float e0 = expf(u0 - m), e1 = expf(u1 - m);
        float s = e0 + e1;
        #pragma unroll
        for (int off = 32; off > 0; off >>= 1)
            s += __shfl_xor(s, off, 64);
        if (lane == 0) red[4 + wave] = s;
        __syncthreads();
        s = (red[4] + red[5]) + (red[6] + red[7]);
        const float inv = 1.f / s;
        o0 = fmaf(e0, inv, o0);
        o1 = fmaf(e1, inv, o1);
        __syncthreads();                 // protect red[] reuse
    }
    out[b * H_ + j0]     = o0;
    out[b * H_ + j0 + 1] = o1;
}

// ------------------------------------------------------------------
// firing_rates[h] = sum_b fire[b,h] / (B*T), layers 0 and 1.
// ------------------------------------------------------------------
__global__ __launch_bounds__(256) void fire_reduce_kernel(
    const float* __restrict__ fire, float* __restrict__ out)
{
    const int h = blockIdx.x * 256 + threadIdx.x;
    if (h >= H_) return;
    const float inv = 1.f / (float)(B_ * T_);
    float s = 0.f;
    for (int b = 0; b < B_; ++b) s += fire[b * H_ + h];
    out[h] = s * inv;
    s = 0.f;
    for (int b = 0; b < B_; ++b) s += fire[B_ * H_ + b * H_ + h];
    out[H_ + h] = s * inv;
}

extern "C" void kernel_launch(void* const* d_in, const int* in_sizes, int n_in,
                              void* d_out, int out_size, void* d_ws, size_t ws_size,
                              hipStream_t stream)
{
    const float* x      = (const float*)d_in[0];
    const float* W0     = (const float*)d_in[1];
    const float* V0     = (const float*)d_in[2];
    const float* alpha0 = (const float*)d_in[3];
    const float* W1     = (const float*)d_in[4];
    const float* V1     = (const float*)d_in[5];
    const float* alpha1 = (const float*)d_in[6];
    const float* Wr     = (const float*)d_in[7];
    const float* alphar = (const float*)d_in[8];
    const float* ut0_0  = (const float*)d_in[9];
    const float* st0_0  = (const float*)d_in[10];
    const float* ut0_1  = (const float*)d_in[11];
    const float* st0_1  = (const float*)d_in[12];
    const float* ut0_r  = (const float*)d_in[13];
    float* out = (float*)d_out;

    const size_t NBTH = (size_t)B_ * T_ * H_;
    float* buf0 = (float*)d_ws;          // Wx0 -> Wx1 -> Wxr
    float* buf1 = buf0 + NBTH;           // s0  -> s1
    float* fire = buf1 + NBTH;           // [2, B, H] spike counts

    dim3 gG(32000 / 64, 512 / 64);
    // Wx0 = x @ W0^T
    gemm_bt_kernel<<<gG, 256, 0, stream>>>(x, W0, buf0, 32000, 512, 700);
    // s0 = RLIF(Wx0, V0)
    rlif_kernel<<<32, 256, 0, stream>>>(buf0, V0, alpha0, ut0_0, st0_0, buf1, fire);
    // Wx1 = s0 @ W1^T
    gemm_bt_kernel<<<gG, 256, 0, stream>>>(buf1, W1, buf0, 32000, 512, 512);
    // s1 = RLIF(Wx1, V1)
    rlif_kernel<<<32, 256, 0, stream>>>(buf0, V1, alpha1, ut0_1, st0_1, buf1, fire + B_ * H_);
    // Wxr = s1 @ Wr^T
    gemm_bt_kernel<<<gG, 256, 0, stream>>>(buf1, Wr, buf0, 32000, 512, 512);
    // out = sum_t softmax(leaky(Wxr))
    readout_kernel<<<32, 256, 0, stream>>>(buf0, alphar, ut0_r, out);
    // firing rates
    fire_reduce_kernel<<<2, 256, 0, stream>>>(fire, out + B_ * H_);
}

// Round 2
// 1796.174 us; speedup vs baseline: 1.5301x; 1.5301x over previous
//
#include <hip/hip_runtime.h>

#define H_   512
#define T_   1000
#define B_   32
#define FIN_ 700
#define C_   50     // readout chunks
#define L_   20     // chunk length (C_*L_ == T_)

static __device__ __forceinline__ float clampAlpha(float a) {
    const float AMIN = 0.8187307530779818f;   // exp(-1/5)
    const float AMAX = 0.9607894391523232f;   // exp(-1/25)
    return fminf(fmaxf(a, AMIN), AMAX);
}

// ------------------------------------------------------------------
// C[m,n] = sum_k A[m,k] * Bt[n,k]   (A: [M,K] row-major, Bt: [N,K])
// 64x64 tile, BK=16, 256 threads, 4x4 microtile per thread.
// ------------------------------------------------------------------
__global__ __launch_bounds__(256) void gemm_bt_kernel(
    const float* __restrict__ A, const float* __restrict__ Bt,
    float* __restrict__ C, int M, int N, int K)
{
    __shared__ __align__(16) float As[16][68];
    __shared__ __align__(16) float Bs[16][68];
    const int tid = threadIdx.x;
    const int bm = blockIdx.x * 64;
    const int bn = blockIdx.y * 64;
    const int tx = tid & 15, ty = tid >> 4;
    const int lrow = tid >> 2;          // 0..63
    const int lk   = (tid & 3) << 2;    // 0,4,8,12
    float acc[4][4] = {};
    const float* Arow = A + (size_t)(bm + lrow) * K;
    const float* Brow = Bt + (size_t)(bn + lrow) * K;

    for (int k0 = 0; k0 < K; k0 += 16) {
        const int ka = k0 + lk;
        float4 av, bv;
        if (ka + 3 < K) {
            av = *reinterpret_cast<const float4*>(Arow + ka);
            bv = *reinterpret_cast<const float4*>(Brow + ka);
        } else {
            float a_[4], b_[4];
            #pragma unroll
            for (int i = 0; i < 4; ++i) {
                a_[i] = (ka + i < K) ? Arow[ka + i] : 0.f;
                b_[i] = (ka + i < K) ? Brow[ka + i] : 0.f;
            }
            av = make_float4(a_[0], a_[1], a_[2], a_[3]);
            bv = make_float4(b_[0], b_[1], b_[2], b_[3]);
        }
        __syncthreads();
        As[lk + 0][lrow] = av.x; As[lk + 1][lrow] = av.y;
        As[lk + 2][lrow] = av.z; As[lk + 3][lrow] = av.w;
        Bs[lk + 0][lrow] = bv.x; Bs[lk + 1][lrow] = bv.y;
        Bs[lk + 2][lrow] = bv.z; Bs[lk + 3][lrow] = bv.w;
        __syncthreads();
        #pragma unroll
        for (int kk = 0; kk < 16; ++kk) {
            const float4 a4 = *reinterpret_cast<const float4*>(&As[kk][ty << 2]);
            const float4 b4 = *reinterpret_cast<const float4*>(&Bs[kk][tx << 2]);
            const float aa[4] = {a4.x, a4.y, a4.z, a4.w};
            const float bb[4] = {b4.x, b4.y, b4.z, b4.w};
            #pragma unroll
            for (int i = 0; i < 4; ++i)
                #pragma unroll
                for (int j = 0; j < 4; ++j)
                    acc[i][j] = fmaf(aa[i], bb[j], acc[i][j]);
        }
    }
    #pragma unroll
    for (int i = 0; i < 4; ++i) {
        const float4 r = make_float4(acc[i][0], acc[i][1], acc[i][2], acc[i][3]);
        *reinterpret_cast<float4*>(&C[(size_t)(bm + ty * 4 + i) * N + bn + tx * 4]) = r;
    }
}

// ------------------------------------------------------------------
// RLIF recurrence, one workgroup per batch (sequential, thresholded).
// ------------------------------------------------------------------
__global__ __launch_bounds__(256) void rlif_kernel(
    const float* __restrict__ Wx,   // [B,T,H]
    const float* __restrict__ V,    // [H,H]
    const float* __restrict__ alpha,// [H]
    const float* __restrict__ ut0,  // [B,H]
    const float* __restrict__ st0,  // [B,H]
    float* __restrict__ s_out,      // [B,T,H]
    float* __restrict__ fire)       // [B,H] spike counts
{
    const int b = blockIdx.x;
    const int tid = threadIdx.x;
    const int j0 = tid * 2;
    __shared__ int act[H_];
    __shared__ int cnt;

    const float a0 = clampAlpha(alpha[j0]);
    const float a1 = clampAlpha(alpha[j0 + 1]);
    const float om0 = 1.f - a0, om1 = 1.f - a1;
    float u0 = ut0[b * H_ + j0], u1 = ut0[b * H_ + j0 + 1];
    float s0 = st0[b * H_ + j0], s1 = st0[b * H_ + j0 + 1];
    const float vd0 = V[(size_t)j0 * H_ + j0];
    const float vd1 = V[(size_t)(j0 + 1) * H_ + (j0 + 1)];
    float f0 = 0.f, f1 = 0.f;
    const float* wxb  = Wx + (size_t)b * T_ * H_;
    float*       sob  = s_out + (size_t)b * T_ * H_;
    const float* st0b = st0 + b * H_;
    int n_act = 0;
    __syncthreads();

    for (int t = 0; t < T_; ++t) {
        float rec0 = 0.f, rec1 = 0.f;
        if (t == 0) {
            for (int h = 0; h < H_; ++h) {
                const float s = st0b[h];
                const float2 v = *reinterpret_cast<const float2*>(&V[(size_t)h * H_ + j0]);
                rec0 = fmaf(s, v.x, rec0);
                rec1 = fmaf(s, v.y, rec1);
            }
        } else {
            for (int i = 0; i < n_act; ++i) {
                const int h = act[i];
                const float2 v = *reinterpret_cast<const float2*>(&V[(size_t)h * H_ + j0]);
                rec0 += v.x; rec1 += v.y;
            }
        }
        rec0 -= s0 * vd0;
        rec1 -= s1 * vd1;
        const float2 wx = *reinterpret_cast<const float2*>(&wxb[(size_t)t * H_ + j0]);
        u0 = a0 * (u0 - s0) + om0 * (wx.x + rec0);
        u1 = a1 * (u1 - s1) + om1 * (wx.y + rec1);
        s0 = (u0 > 1.f) ? 1.f : 0.f;
        s1 = (u1 > 1.f) ? 1.f : 0.f;
        f0 += s0; f1 += s1;
        *reinterpret_cast<float2*>(&sob[(size_t)t * H_ + j0]) = make_float2(s0, s1);

        __syncthreads();
        if (tid == 0) cnt = 0;
        __syncthreads();
        if (s0 != 0.f) { const int p = atomicAdd(&cnt, 1); act[p] = j0; }
        if (s1 != 0.f) { const int p = atomicAdd(&cnt, 1); act[p] = j0 + 1; }
        __syncthreads();
        n_act = cnt;
    }
    fire[b * H_ + j0]     = f0;
    fire[b * H_ + j0 + 1] = f1;
}

// ------------------------------------------------------------------
// Readout, parallel-scan decomposition over T.
// Pass 1: per-chunk scan with zero initial state -> u_end[b,c,:]
// ------------------------------------------------------------------
__global__ __launch_bounds__(256) void ro_partial_kernel(
    const float* __restrict__ Wx,    // [B,T,H]
    const float* __restrict__ alpha,
    float* __restrict__ u_end)       // [B,C,H]
{
    const int b = blockIdx.x;
    const int c = blockIdx.y;
    const int j0 = threadIdx.x * 2;
    const float a0 = clampAlpha(alpha[j0]);
    const float a1 = clampAlpha(alpha[j0 + 1]);
    const float om0 = 1.f - a0, om1 = 1.f - a1;
    float u0 = 0.f, u1 = 0.f;
    const float* wxb = Wx + ((size_t)b * T_ + (size_t)c * L_) * H_;
    #pragma unroll 4
    for (int t = 0; t < L_; ++t) {
        const float2 wx = *reinterpret_cast<const float2*>(&wxb[(size_t)t * H_ + j0]);
        u0 = fmaf(a0, u0, om0 * wx.x);
        u1 = fmaf(a1, u1, om1 * wx.y);
    }
    float* ue = u_end + ((size_t)b * C_ + c) * H_;
    *reinterpret_cast<float2*>(&ue[j0]) = make_float2(u0, u1);
}

// ------------------------------------------------------------------
// Pass 2: sequential carry combine over the C chunks (cheap).
// carry[b,c] = state at the START of chunk c.
// ------------------------------------------------------------------
__global__ __launch_bounds__(256) void ro_carry_kernel(
    const float* __restrict__ u_end, // [B,C,H]
    const float* __restrict__ alpha,
    const float* __restrict__ ut0,   // [B,H]
    float* __restrict__ carry)       // [B,C,H]
{
    const int b = blockIdx.x;
    const int j0 = threadIdx.x * 2;
    const float a0 = clampAlpha(alpha[j0]);
    const float a1 = clampAlpha(alpha[j0 + 1]);
    const float aL0 = powf(a0, (float)L_);
    const float aL1 = powf(a1, (float)L_);
    float c0 = ut0[b * H_ + j0];
    float c1 = ut0[b * H_ + j0 + 1];
    for (int c = 0; c < C_; ++c) {
        float* cr = carry + ((size_t)b * C_ + c) * H_;
        *reinterpret_cast<float2*>(&cr[j0]) = make_float2(c0, c1);
        const float2 ue = *reinterpret_cast<const float2*>(
            &u_end[((size_t)b * C_ + c) * H_ + j0]);
        c0 = fmaf(aL0, c0, ue.x);
        c1 = fmaf(aL1, c1, ue.y);
    }
}

// ------------------------------------------------------------------
// Pass 3: re-scan each chunk from its true carry; softmax per step;
// accumulate per-chunk partial output sums (no atomics).
// ------------------------------------------------------------------
__global__ __launch_bounds__(256) void ro_softmax_kernel(
    const float* __restrict__ Wx,    // [B,T,H]
    const float* __restrict__ alpha,
    const float* __restrict__ carry, // [B,C,H]
    float* __restrict__ opart)       // [C,B,H]
{
    const int b = blockIdx.x;
    const int c = blockIdx.y;
    const int tid = threadIdx.x;
    const int j0 = tid * 2;
    __shared__ float red[8];
    const float a0 = clampAlpha(alpha[j0]);
    const float a1 = clampAlpha(alpha[j0 + 1]);
    const float om0 = 1.f - a0, om1 = 1.f - a1;
    float2 u = *reinterpret_cast<const float2*>(
        &carry[((size_t)b * C_ + c) * H_ + j0]);
    float u0 = u.x, u1 = u.y;
    float o0 = 0.f, o1 = 0.f;
    const float* wxb = Wx + ((size_t)b * T_ + (size_t)c * L_) * H_;
    const int wave = tid >> 6;
    const int lane = tid & 63;

    for (int t = 0; t < L_; ++t) {
        const float2 wx = *reinterpret_cast<const float2*>(&wxb[(size_t)t * H_ + j0]);
        u0 = fmaf(a0, u0, om0 * wx.x);
        u1 = fmaf(a1, u1, om1 * wx.y);
        float m = fmaxf(u0, u1);
        #pragma unroll
        for (int off = 32; off > 0; off >>= 1)
            m = fmaxf(m, __shfl_xor(m, off, 64));
        if (lane == 0) red[wave] = m;
        __syncthreads();
        m = fmaxf(fmaxf(red[0], red[1]), fmaxf(red[2], red[3]));
        const float e0 = expf(u0 - m), e1 = expf(u1 - m);
        float s = e0 + e1;
        #pragma unroll
        for (int off = 32; off > 0; off >>= 1)
            s += __shfl_xor(s, off, 64);
        if (lane == 0) red[4 + wave] = s;
        __syncthreads();
        s = (red[4] + red[5]) + (red[6] + red[7]);
        const float inv = 1.f / s;
        o0 = fmaf(e0, inv, o0);
        o1 = fmaf(e1, inv, o1);
        __syncthreads();
    }
    float* op = opart + ((size_t)c * B_ + b) * H_;
    *reinterpret_cast<float2*>(&op[j0]) = make_float2(o0, o1);
}

// out[b,h] = sum_c opart[c,b,h]
__global__ __launch_bounds__(256) void ro_reduce_kernel(
    const float* __restrict__ opart, float* __restrict__ out)
{
    const int idx = blockIdx.x * 256 + threadIdx.x;  // 0 .. B*H-1
    float s = 0.f;
    for (int c = 0; c < C_; ++c) s += opart[(size_t)c * B_ * H_ + idx];
    out[idx] = s;
}

// firing_rates[h] = sum_b fire[b,h] / (B*T), layers 0 and 1.
__global__ __launch_bounds__(256) void fire_reduce_kernel(
    const float* __restrict__ fire, float* __restrict__ out)
{
    const int h = blockIdx.x * 256 + threadIdx.x;
    if (h >= H_) return;
    const float inv = 1.f / (float)(B_ * T_);
    float s = 0.f;
    for (int b = 0; b < B_; ++b) s += fire[b * H_ + h];
    out[h] = s * inv;
    s = 0.f;
    for (int b = 0; b < B_; ++b) s += fire[B_ * H_ + b * H_ + h];
    out[H_ + h] = s * inv;
}

extern "C" void kernel_launch(void* const* d_in, const int* in_sizes, int n_in,
                              void* d_out, int out_size, void* d_ws, size_t ws_size,
                              hipStream_t stream)
{
    const float* x      = (const float*)d_in[0];
    const float* W0     = (const float*)d_in[1];
    const float* V0     = (const float*)d_in[2];
    const float* alpha0 = (const float*)d_in[3];
    const float* W1     = (const float*)d_in[4];
    const float* V1     = (const float*)d_in[5];
    const float* alpha1 = (const float*)d_in[6];
    const float* Wr     = (const float*)d_in[7];
    const float* alphar = (const float*)d_in[8];
    const float* ut0_0  = (const float*)d_in[9];
    const float* st0_0  = (const float*)d_in[10];
    const float* ut0_1  = (const float*)d_in[11];
    const float* st0_1  = (const float*)d_in[12];
    const float* ut0_r  = (const float*)d_in[13];
    float* out = (float*)d_out;

    const size_t NBTH = (size_t)B_ * T_ * H_;
    const size_t NBCH = (size_t)B_ * C_ * H_;
    float* buf0  = (float*)d_ws;          // Wx0 -> Wx1 -> Wxr
    float* buf1  = buf0 + NBTH;           // s0  -> s1
    float* fire  = buf1 + NBTH;           // [2, B, H]
    float* u_end = fire + 2 * B_ * H_;    // [B, C, H]
    float* carry = u_end + NBCH;          // [B, C, H]
    float* opart = carry + NBCH;          // [C, B, H]

    dim3 gG(32000 / 64, 512 / 64);
    // Wx0 = x @ W0^T
    gemm_bt_kernel<<<gG, 256, 0, stream>>>(x, W0, buf0, 32000, 512, 700);
    // s0 = RLIF(Wx0, V0)
    rlif_kernel<<<32, 256, 0, stream>>>(buf0, V0, alpha0, ut0_0, st0_0, buf1, fire);
    // Wx1 = s0 @ W1^T
    gemm_bt_kernel<<<gG, 256, 0, stream>>>(buf1, W1, buf0, 32000, 512, 512);
    // s1 = RLIF(Wx1, V1)
    rlif_kernel<<<32, 256, 0, stream>>>(buf0, V1, alpha1, ut0_1, st0_1, buf1, fire + B_ * H_);
    // Wxr = s1 @ Wr^T
    gemm_bt_kernel<<<gG, 256, 0, stream>>>(buf1, Wr, buf0, 32000, 512, 512);
    // Readout: parallel scan + softmax partials + reduce
    ro_partial_kernel<<<dim3(B_, C_), 256, 0, stream>>>(buf0, alphar, u_end);
    ro_carry_kernel<<<B_, 256, 0, stream>>>(u_end, alphar, ut0_r, carry);
    ro_softmax_kernel<<<dim3(B_, C_), 256, 0, stream>>>(buf0, alphar, carry, opart);
    ro_reduce_kernel<<<(B_ * H_) / 256, 256, 0, stream>>>(opart, out);
    // firing rates
    fire_reduce_kernel<<<2, 256, 0, stream>>>(fire, out + B_ * H_);
}